// Round 14
// baseline (93.425 us; speedup 1.0000x reference)
//
#include <hip/hip_runtime.h>
#include <math.h>

#define SEQ 2048
#define DIM 128
#define NTILES 64            // 32-key tiles per batch
#define NT4 16               // tiles per kv-quarter
#define KTB 8192             // K'' tile: 8 frags [s*4+c][lane][16B]
#define VTB 9216             // V' tile: 9 frags [n][lane][16B] (frag 8 = t-pad row)

typedef __attribute__((ext_vector_type(8))) short bf16x8;
typedef __attribute__((ext_vector_type(4))) float f32x4;
typedef __attribute__((ext_vector_type(4))) short short4v;

union frag_u { bf16x8 h; unsigned u[4]; };

__device__ __forceinline__ short f2bf(float f) {
  union { float f; unsigned u; } v; v.f = f;
  unsigned r = v.u + 0x7FFFu + ((v.u >> 16) & 1u);  // RNE
  return (short)(r >> 16);
}
__device__ __forceinline__ unsigned cvtpk(float lo, float hi) {
  unsigned r;
  asm("v_cvt_pk_bf16_f32 %0, %1, %2" : "=v"(r) : "v"(lo), "v"(hi));
  return r;
}

// ===== pre-pass (16x16 geometry): K'' = K*(t*log2e/sqrtD); V' = t*V (+ t-pad row) =====
// K frag f=s*4+c, lane l: key = 32*tile + 16s + (l&15), d = 32c + (l>>4)*8 + j
// V frag n<8,  lane l: d = 16n + (l&15),  k = (l>>4)*8 + j, value = t[k]*V[k][d]
// V frag n=8 (pad), lane l: row (l&15); row0 = t[k], else 0  -> PV output row0 = denominator
__global__ __launch_bounds__(256)
void prepack_kernel(const float* __restrict__ Kg, const float* __restrict__ Vg,
                    const float* __restrict__ Tg,
                    char* __restrict__ Kws, char* __restrict__ Vws) {
  const int tile = blockIdx.x, b = blockIdx.y;
  const int tid = (int)threadIdx.x;
  const float* Kb = Kg + ((size_t)b * SEQ + tile * 32) * DIM;
  const float* Vb = Vg + ((size_t)b * SEQ + tile * 32) * DIM;
  const float* Tb = Tg + (size_t)b * SEQ + tile * 32;
  char* kd = Kws + (size_t)(b * NTILES + tile) * KTB;
  char* vd = Vws + (size_t)(b * NTILES + tile) * VTB;

  #pragma unroll
  for (int i = 0; i < 2; ++i) {
    int id = i * 256 + tid;            // 0..511 = 8 frags x 64 lanes
    int f = id >> 6, l = id & 63;
    int s = f >> 2, c = f & 3;
    int krow = s * 16 + (l & 15);
    int dstart = c * 32 + (l >> 4) * 8;
    float sc = Tb[krow] * 0.12751743f; // t * log2(e)/sqrt(128)
    const float4 f0 = *(const float4*)(Kb + (size_t)krow * DIM + dstart);
    const float4 f1 = *(const float4*)(Kb + (size_t)krow * DIM + dstart + 4);
    bf16x8 pk;
    pk[0]=f2bf(f0.x*sc); pk[1]=f2bf(f0.y*sc); pk[2]=f2bf(f0.z*sc); pk[3]=f2bf(f0.w*sc);
    pk[4]=f2bf(f1.x*sc); pk[5]=f2bf(f1.y*sc); pk[6]=f2bf(f1.z*sc); pk[7]=f2bf(f1.w*sc);
    *(bf16x8*)(kd + id * 16) = pk;
  }
  #pragma unroll
  for (int i = 0; i < 2; ++i) {
    int id = i * 256 + tid;            // 0..511 = frags 0..7
    int n = id >> 6, l = id & 63;
    int d = n * 16 + (l & 15);
    int k0 = (l >> 4) * 8;
    bf16x8 pk;
    #pragma unroll
    for (int j = 0; j < 8; ++j)
      pk[j] = f2bf(Tb[k0 + j] * Vb[(size_t)(k0 + j) * DIM + d]);
    *(bf16x8*)(vd + id * 16) = pk;
  }
  if (tid < 64) {                      // pad frag 8
    int l = tid;
    int k0 = (l >> 4) * 8;
    bf16x8 pk;
    #pragma unroll
    for (int j = 0; j < 8; ++j)
      pk[j] = ((l & 15) == 0) ? f2bf(Tb[k0 + j]) : (short)0;
    *(bf16x8*)(vd + 8192 + l * 16) = pk;
  }
}

// ===== main: 16x16 MFMA; wave = 16 q x full D; 4 waves = 4 kv-quarters; 4 waves/SIMD =====
__global__ __launch_bounds__(256, 4)
void trust_attn_main(const float* __restrict__ Qg, const char* __restrict__ Kws,
                     const char* __restrict__ Vws, float* __restrict__ Og, int swz) {
  __shared__ __align__(16) char smem[16640];   // A0 8K | A1 8K | Zx[4][16]

  // bijective XCD map (grid 2048 = 16 b x 128 qblk): each XCD owns 2 batches
  const int bid = (int)blockIdx.x;
  int b, qblk;
  if (swz) { int xcd = bid & 7, idx = bid >> 3; b = xcd * 2 + (idx >> 7); qblk = idx & 127; }
  else     { b = bid >> 7; qblk = bid & 127; }

  const int tid = (int)threadIdx.x;
  const int w  = tid >> 6;          // kv quarter
  const int l  = tid & 63;
  const int a  = l >> 4, ql = l & 15;
  const int q  = qblk * 16 + ql;

  const float* Qr = Qg + ((size_t)b * SEQ + q) * DIM;
  const char* Kt = Kws + (size_t)(b * NTILES + w * NT4) * KTB + l * 16;
  const char* Vt = Vws + (size_t)(b * NTILES + w * NT4) * VTB + l * 16;

  // Q fragments (B-operand): col = q = l&15; chunk c: d = 32c + a*8 + j
  frag_u qf[4];
  #pragma unroll
  for (int c = 0; c < 4; ++c) {
    const float4 x = *(const float4*)(Qr + c * 32 + a * 8);
    const float4 y = *(const float4*)(Qr + c * 32 + a * 8 + 4);
    bf16x8 q8;
    q8[0]=f2bf(x.x); q8[1]=f2bf(x.y); q8[2]=f2bf(x.z); q8[3]=f2bf(x.w);
    q8[4]=f2bf(y.x); q8[5]=f2bf(y.y); q8[6]=f2bf(y.z); q8[7]=f2bf(y.w);
    qf[c].h = q8;
  }

  f32x4 acc[8];
  #pragma unroll
  for (int n = 0; n < 8; ++n) acc[n] = f32x4{0.f, 0.f, 0.f, 0.f};
  f32x4 accp = f32x4{0.f, 0.f, 0.f, 0.f};   // pad output: row0 = denominator

  const int addrA = (((a & 1) * 2) * 16 + ql) * 4;  // src lane group 2*(a&1)
  const int addrB = addrA + 64;                     // src lane group 2*(a&1)+1
  const bool lotile = (a < 2);                      // this lane consumes S-tile (a>>1)

  for (int t = 0; t < NT4; ++t) {
    // ---- K frags (current tile; 4-wave TLP hides the L2 latency) ----
    frag_u kf[8];
    #pragma unroll
    for (int f = 0; f < 8; ++f)
      kf[f].h = *(const bf16x8*)(Kt + (size_t)t * KTB + f * 1024);

    // ---- swapped QK: S[k=row][q=col]; two independent 4-deep chains ----
    f32x4 S0 = f32x4{0.f,0.f,0.f,0.f}, S1 = f32x4{0.f,0.f,0.f,0.f};
    __builtin_amdgcn_s_setprio(1);
    #pragma unroll
    for (int c = 0; c < 4; ++c) {
      S0 = __builtin_amdgcn_mfma_f32_16x16x32_bf16(kf[c].h,     qf[c].h, S0, 0, 0, 0);
      S1 = __builtin_amdgcn_mfma_f32_16x16x32_bf16(kf[4 + c].h, qf[c].h, S1, 0, 0, 0);
    }
    __builtin_amdgcn_s_setprio(0);

    // ---- V' frags (issued here; covered by exp+pack+bpermute) ----
    frag_u vf[9];
    #pragma unroll
    for (int n = 0; n < 9; ++n)
      vf[n].h = *(const bf16x8*)(Vt + (size_t)t * VTB + n * 1024);

    // ---- p = 2^S (t folded into K''); lane holds k = 16s + 4a + r, q = ql ----
    float p0[4], p1[4];
    #pragma unroll
    for (int r = 0; r < 4; ++r) {
      p0[r] = __builtin_amdgcn_exp2f(S0[r]);
      p1[r] = __builtin_amdgcn_exp2f(S1[r]);
    }

    // ---- pack + redistribute: lane needs P[k=8a..8a+8)[q=ql] as 4 bf16-pair words.
    // k=8a+2m: src tile s=a>>1, src group 2(a&1)+(m>>1), word m&1.  8 bpermute + 4 select.
    unsigned u00 = cvtpk(p0[0], p0[1]), u01 = cvtpk(p0[2], p0[3]);
    unsigned u10 = cvtpk(p1[0], p1[1]), u11 = cvtpk(p1[2], p1[3]);
    int sA0 = __builtin_amdgcn_ds_bpermute(addrA, (int)u00);
    int sA1 = __builtin_amdgcn_ds_bpermute(addrA, (int)u01);
    int sB0 = __builtin_amdgcn_ds_bpermute(addrB, (int)u00);
    int sB1 = __builtin_amdgcn_ds_bpermute(addrB, (int)u01);
    int tA0 = __builtin_amdgcn_ds_bpermute(addrA, (int)u10);
    int tA1 = __builtin_amdgcn_ds_bpermute(addrA, (int)u11);
    int tB0 = __builtin_amdgcn_ds_bpermute(addrB, (int)u10);
    int tB1 = __builtin_amdgcn_ds_bpermute(addrB, (int)u11);
    frag_u PA;
    PA.u[0] = lotile ? (unsigned)sA0 : (unsigned)tA0;
    PA.u[1] = lotile ? (unsigned)sA1 : (unsigned)tA1;
    PA.u[2] = lotile ? (unsigned)sB0 : (unsigned)tB0;
    PA.u[3] = lotile ? (unsigned)sB1 : (unsigned)tB1;

    // ---- PV: 9 independent MFMAs (8 output d-tiles + denominator pad) ----
    __builtin_amdgcn_s_setprio(1);
    #pragma unroll
    for (int n = 0; n < 8; ++n)
      acc[n] = __builtin_amdgcn_mfma_f32_16x16x32_bf16(vf[n].h, PA.h, acc[n], 0, 0, 0);
    accp = __builtin_amdgcn_mfma_f32_16x16x32_bf16(vf[8].h, PA.h, accp, 0, 0, 0);
    __builtin_amdgcn_s_setprio(0);
  }

  // ---- epilogue: 4-quarter combine. acc[n][r]: d = 16n+4a+r, q = ql.
  //      accp[0] on lanes a==0 = this quarter's denominator for q = ql. ----
  float* A0 = (float*)smem;            // [16 q][128 d] f32, byte ^((q&7)<<4)
  float* A1 = (float*)(smem + 8192);
  float* Zx = (float*)(smem + 16384);  // [4][16]

  if (l < 16) Zx[w * 16 + l] = accp[0];
  if (w == 1 || w == 3) {
    float* A = (w == 1) ? A0 : A1;
    #pragma unroll
    for (int n = 0; n < 8; ++n) {
      int byte_off = (ql * 512 + n * 64 + a * 16) ^ ((ql & 7) << 4);
      *(f32x4*)((char*)A + byte_off) = acc[n];
    }
  }
  __syncthreads();
  if (w == 0 || w == 2) {
    float* A = (w == 0) ? A0 : A1;
    #pragma unroll
    for (int n = 0; n < 8; ++n) {
      int byte_off = (ql * 512 + n * 64 + a * 16) ^ ((ql & 7) << 4);
      f32x4 o = *(const f32x4*)((const char*)A + byte_off);
      o[0] += acc[n][0]; o[1] += acc[n][1]; o[2] += acc[n][2]; o[3] += acc[n][3];
      *(f32x4*)((char*)A + byte_off) = o;
    }
  }
  __syncthreads();
  {
    const float z = Zx[ql] + Zx[16 + ql] + Zx[32 + ql] + Zx[48 + ql];
    const float inv = 1.0f / z;
    float* orow = Og + ((size_t)b * SEQ + qblk * 16 + ql) * DIM;
    const int d0 = w * 32 + a * 8;
    #pragma unroll
    for (int u = 0; u < 2; ++u) {
      int d = d0 + u * 4;
      int byte_off = (ql * 512 + d * 4) ^ ((ql & 7) << 4);
      f32x4 x0 = *(const f32x4*)((const char*)A0 + byte_off);
      f32x4 x1 = *(const f32x4*)((const char*)A1 + byte_off);
      float4 r;
      r.x = (x0[0] + x1[0]) * inv;
      r.y = (x0[1] + x1[1]) * inv;
      r.z = (x0[2] + x1[2]) * inv;
      r.w = (x0[3] + x1[3]) * inv;
      *(float4*)(orow + d) = r;
    }
  }
}

// ===== fallback (validated R3 monolithic) for small ws =====
__global__ __launch_bounds__(256, 2)
void trust_attn_fallback(const float* __restrict__ Qg, const float* __restrict__ Kg,
                         const float* __restrict__ Vg, const float* __restrict__ Tg,
                         float* __restrict__ Og) {
  __shared__ short Klds[2][64 * DIM];
  __shared__ short Vlds[2][DIM * 64];
  __shared__ short Plds[4][16 * 64];
  __shared__ float Tlds[2][64];

  const int b = blockIdx.y;
  const int qbase = blockIdx.x * 64;
  const int tid = (int)threadIdx.x;
  const int w = tid >> 6;
  const int l = tid & 63;
  const int lr = l & 15;
  const int lg = l >> 4;

  const float* Qb = Qg + (size_t)b * SEQ * DIM;
  const float* Kb = Kg + (size_t)b * SEQ * DIM;
  const float* Vb = Vg + (size_t)b * SEQ * DIM;
  const float* Tb = Tg + (size_t)b * SEQ;
  float*       Ob = Og + (size_t)b * SEQ * DIM;

  float4 kreg[8];
  float  vreg[32];
  float  treg;

  auto ISSUE = [&](int kv0) {
    #pragma unroll
    for (int i = 0; i < 8; ++i) {
      int flat4 = i * 256 + tid;
      int r = flat4 >> 5;
      int c4 = (flat4 & 31) << 2;
      kreg[i] = *(const float4*)(Kb + (size_t)(kv0 + r) * DIM + c4);
    }
    #pragma unroll
    for (int i = 0; i < 4; ++i) {
      int task = i * 256 + tid;
      int d = task & 127;
      int chunk = task >> 7;
      const float* src = Vb + (size_t)(kv0 + chunk * 8) * DIM + d;
      #pragma unroll
      for (int j = 0; j < 8; ++j) vreg[i * 8 + j] = src[(size_t)j * DIM];
    }
    treg = (tid < 64) ? Tb[kv0 + tid] : 0.f;
  };

  auto STORE = [&](int buf) {
    #pragma unroll
    for (int i = 0; i < 8; ++i) {
      int flat4 = i * 256 + tid;
      int r = flat4 >> 5;
      int c4 = (flat4 & 31) << 2;
      short4v pk;
      pk[0] = f2bf(kreg[i].x); pk[1] = f2bf(kreg[i].y);
      pk[2] = f2bf(kreg[i].z); pk[3] = f2bf(kreg[i].w);
      int byte_off = (r * 256 + (c4 << 1)) ^ ((r & 7) << 4);
      *(short4v*)((char*)&Klds[buf][0] + byte_off) = pk;
    }
    #pragma unroll
    for (int i = 0; i < 4; ++i) {
      int task = i * 256 + tid;
      int d = task & 127;
      int chunk = task >> 7;
      bf16x8 pk;
      #pragma unroll
      for (int j = 0; j < 8; ++j) pk[j] = f2bf(vreg[i * 8 + j]);
      int byte_off = (d * 128 + chunk * 16) ^ ((d & 7) << 4);
      *(bf16x8*)((char*)&Vlds[buf][0] + byte_off) = pk;
    }
    if (tid < 64) Tlds[buf][tid] = treg;
  };

  bf16x8 qf[4];
  {
    const float* qrow = Qb + (size_t)(qbase + w * 16 + lr) * DIM;
    #pragma unroll
    for (int kk = 0; kk < 4; ++kk) {
      const float4 a = *(const float4*)(qrow + kk * 32 + lg * 8);
      const float4 c = *(const float4*)(qrow + kk * 32 + lg * 8 + 4);
      bf16x8 f;
      f[0] = f2bf(a.x); f[1] = f2bf(a.y); f[2] = f2bf(a.z); f[3] = f2bf(a.w);
      f[4] = f2bf(c.x); f[5] = f2bf(c.y); f[6] = f2bf(c.z); f[7] = f2bf(c.w);
      qf[kk] = f;
    }
  }

  f32x4 acc[8];
  #pragma unroll
  for (int nt = 0; nt < 8; ++nt) acc[nt] = f32x4{0.f, 0.f, 0.f, 0.f};
  float lsum[4] = {0.f, 0.f, 0.f, 0.f};

  ISSUE(0);
  STORE(0);
  __syncthreads();

  for (int t = 0; t < SEQ / 64; ++t) {
    const int cur = t & 1;
    if (t + 1 < SEQ / 64) ISSUE((t + 1) * 64);

    const short* Kc = &Klds[cur][0];
    const short* Vc = &Vlds[cur][0];

    f32x4 s[4];
    #pragma unroll
    for (int kt = 0; kt < 4; ++kt) {
      f32x4 a0 = f32x4{0.f, 0.f, 0.f, 0.f};
      #pragma unroll
      for (int kk = 0; kk < 4; ++kk) {
        int row = kt * 16 + lr;
        int byte_off = (row * 256 + ((kk * 32 + lg * 8) << 1)) ^ ((row & 7) << 4);
        bf16x8 kf = *(const bf16x8*)((const char*)Kc + byte_off);
        a0 = __builtin_amdgcn_mfma_f32_16x16x32_bf16(qf[kk], kf, a0, 0, 0, 0);
      }
      s[kt] = a0;
    }

    short* Pw = Plds[w];
    #pragma unroll
    for (int kt = 0; kt < 4; ++kt) {
      float tt = Tlds[cur][kt * 16 + lr];
      float tc = tt * 0.12751743f;
      #pragma unroll
      for (int r = 0; r < 4; ++r) {
        float p = tt * exp2f(s[kt][r] * tc);
        lsum[r] += p;
        int qq = lg * 4 + r;
        int byte_off = ((qq * 128) + ((kt * 16 + lr) << 1)) ^ ((qq & 7) << 4);
        *(short*)((char*)Pw + byte_off) = f2bf(p);
      }
    }
    asm volatile("s_waitcnt lgkmcnt(0)" ::: "memory");

    #pragma unroll
    for (int ks = 0; ks < 2; ++ks) {
      int byteA = (lr * 128 + ((ks * 32 + lg * 8) << 1)) ^ ((lr & 7) << 4);
      bf16x8 pf = *(const bf16x8*)((char*)Pw + byteA);
      #pragma unroll
      for (int nt = 0; nt < 8; ++nt) {
        int row = nt * 16 + lr;
        int byteB = (row * 128 + ((ks * 32 + lg * 8) << 1)) ^ ((row & 7) << 4);
        bf16x8 vf = *(const bf16x8*)((const char*)Vc + byteB);
        acc[nt] = __builtin_amdgcn_mfma_f32_16x16x32_bf16(pf, vf, acc[nt], 0, 0, 0);
      }
    }

    if (t + 1 < SEQ / 64) {
      STORE(cur ^ 1);
      __syncthreads();
    }
  }

  #pragma unroll
  for (int r = 0; r < 4; ++r) {
    float v = lsum[r];
    v += __shfl_xor(v, 1);
    v += __shfl_xor(v, 2);
    v += __shfl_xor(v, 4);
    v += __shfl_xor(v, 8);
    float inv = 1.0f / v;
    float* dst = Ob + (size_t)(qbase + w * 16 + lg * 4 + r) * DIM + lr;
    #pragma unroll
    for (int nt = 0; nt < 8; ++nt)
      dst[nt * 16] = acc[nt][r] * inv;
  }
}

extern "C" void kernel_launch(void* const* d_in, const int* in_sizes, int n_in,
                              void* d_out, int out_size, void* d_ws, size_t ws_size,
                              hipStream_t stream) {
  (void)n_in; (void)out_size;
  const float* Q = (const float*)d_in[0];
  const float* K = (const float*)d_in[1];
  const float* V = (const float*)d_in[2];
  const float* T = (const float*)d_in[3];
  float* O = (float*)d_out;
  const int B = in_sizes[0] / (SEQ * DIM);

  const size_t k_bytes = (size_t)B * NTILES * KTB;
  const size_t v_bytes = (size_t)B * NTILES * VTB;
  if (ws_size >= k_bytes + v_bytes) {
    char* Kws = (char*)d_ws;
    char* Vws = Kws + k_bytes;
    dim3 gridp(NTILES, B);
    prepack_kernel<<<gridp, 256, 0, stream>>>(K, V, T, Kws, Vws);
    const int nblk = B * (SEQ / 16);
    const int swz = (B == 16) ? 1 : 0;
    trust_attn_main<<<nblk, 256, 0, stream>>>(Q, Kws, Vws, O, swz);
  } else {
    dim3 grid(SEQ / 64, B);
    trust_attn_fallback<<<grid, 256, 0, stream>>>(Q, K, V, T, O);
  }
}

// Round 15
// 62.175 us; speedup vs baseline: 1.5026x; 1.5026x over previous
//
#include <hip/hip_runtime.h>
#include <math.h>

#define SEQ 2048
#define DIM 128
#define KVB 32
#define NTILES (SEQ / KVB)   // 64
#define NT2 (NTILES / 2)     // 32 tiles per kv-half
#define KTB 8192             // packed K'' tile bytes: [32 k][128 d] bf16, swizzled
#define VTB 8192             // packed V^T tile bytes: [128 d][32 k] bf16, swizzled

typedef __attribute__((ext_vector_type(8))) short bf16x8;
typedef __attribute__((ext_vector_type(16))) float f32x16;
typedef __attribute__((ext_vector_type(4))) short short4v;
typedef __attribute__((ext_vector_type(4))) float f32x4;

union frag_u { bf16x8 h; unsigned u[4]; };

__device__ __forceinline__ short f2bf(float f) {
  union { float f; unsigned u; } v; v.f = f;
  unsigned r = v.u + 0x7FFFu + ((v.u >> 16) & 1u);  // RNE
  return (short)(r >> 16);
}
__device__ __forceinline__ float bf2f(short h) {
  return __uint_as_float(((unsigned)(unsigned short)h) << 16);
}
__device__ __forceinline__ void dma16(const void* g, void* l) {
  __builtin_amdgcn_global_load_lds(
      (const __attribute__((address_space(1))) void*)g,
      (__attribute__((address_space(3))) void*)l, 16, 0, 0);
}
__device__ __forceinline__ unsigned cvtpk(float lo, float hi) {
  unsigned r;
  asm("v_cvt_pk_bf16_f32 %0, %1, %2" : "=v"(r) : "v"(lo), "v"(hi));
  return r;
}
__device__ __forceinline__ void pl32swap(unsigned& a, unsigned& b) {
  asm("v_permlane32_swap_b32 %0, %1" : "+v"(a), "+v"(b));
}

// ===== pre-pass: K'' = K * (t*log2e/sqrtD) swizzled; V^T swizzled; lt = log2(t) split hi+lo =====
__global__ __launch_bounds__(256)
void prepack_kernel(const float* __restrict__ Kg, const float* __restrict__ Vg,
                    const float* __restrict__ Tg,
                    char* __restrict__ Kws, char* __restrict__ Vws,
                    unsigned* __restrict__ Lws) {
  const int tile = blockIdx.x, b = blockIdx.y;
  const int tid = (int)threadIdx.x;
  const float* Kb = Kg + ((size_t)b * SEQ + tile * KVB) * DIM;
  const float* Vb = Vg + ((size_t)b * SEQ + tile * KVB) * DIM;
  const float* Tb = Tg + (size_t)b * SEQ + tile * KVB;
  char* kd = Kws + (size_t)(b * NTILES + tile) * KTB;
  char* vd = Vws + (size_t)(b * NTILES + tile) * VTB;

  // K'': 512 16B chunks = (k 0..31) x (c16 0..15); byte = k*256 + ((c16 ^ (k&7))<<4)
  #pragma unroll
  for (int i = 0; i < 2; ++i) {
    int id = i * 256 + tid;
    int k = id >> 4, c16 = id & 15;
    float sc = Tb[k] * 0.12751743f;  // t * log2(e)/sqrt(128)
    const float4 f0 = *(const float4*)(Kb + (size_t)k * DIM + c16 * 8);
    const float4 f1 = *(const float4*)(Kb + (size_t)k * DIM + c16 * 8 + 4);
    bf16x8 pk;
    pk[0]=f2bf(f0.x*sc); pk[1]=f2bf(f0.y*sc); pk[2]=f2bf(f0.z*sc); pk[3]=f2bf(f0.w*sc);
    pk[4]=f2bf(f1.x*sc); pk[5]=f2bf(f1.y*sc); pk[6]=f2bf(f1.z*sc); pk[7]=f2bf(f1.w*sc);
    *(bf16x8*)(kd + k * 256 + ((c16 ^ (k & 7)) << 4)) = pk;
  }
  // V^T: 512 chunks = (d 0..127) x (ch 0..3, 8 k's each); byte = d*64 + ((ch ^ ((d>>1)&3))<<4)
  #pragma unroll
  for (int i = 0; i < 2; ++i) {
    int id = i * 256 + tid;
    int d = id & 127, ch = id >> 7;
    const float* src = Vb + (size_t)(ch * 8) * DIM + d;
    bf16x8 pk;
    #pragma unroll
    for (int j = 0; j < 8; ++j) pk[j] = f2bf(src[(size_t)j * DIM]);
    *(bf16x8*)(vd + d * 64 + ((ch ^ ((d >> 1) & 3)) << 4)) = pk;
  }
  if (tid < KVB) {
    float t = Tb[tid];
    float lt = log2f(t);
    short h = f2bf(lt);
    short lo = f2bf(lt - bf2f(h));  // lt_hi + lt_lo == lt to ~3e-5
    Lws[(size_t)b * SEQ + tile * KVB + tid] =
        (unsigned)(unsigned short)h | ((unsigned)(unsigned short)lo << 16);
  }
}

// ===== main (R7 structure + T15 two-tile pipeline): QK(t) interleaved with PV(t-1) =====
__global__ __launch_bounds__(256, 2)
void trust_attn_main(const float* __restrict__ Qg, const char* __restrict__ Kws,
                     const char* __restrict__ Vws, const unsigned* __restrict__ Lws,
                     float* __restrict__ Og, int swz) {
  // KL: [h*2+buf]*8192 at 0 (32 KB) | VL: same layout at 32768 (32 KB)
  __shared__ __align__(16) char smem[65536];

  // bijective XCD mapping (grid 512 = 16 b x 32 qblk): each XCD owns 2 batches
  const int bid = (int)blockIdx.x;
  int b, qblk;
  if (swz) { int xcd = bid & 7, idx = bid >> 3; b = xcd * 2 + (idx >> 5); qblk = idx & 31; }
  else     { b = bid >> 5; qblk = bid & 31; }

  const int tid = (int)threadIdx.x;
  const int h   = tid >> 7;         // kv half: keys [h*1024, h*1024+1024)
  const int gq  = (tid >> 6) & 1;   // q sub-block
  const int l   = tid & 63;
  const int hi  = l >> 5, l31 = l & 31;
  const int t128 = tid & 127;
  const int qcol = qblk * 64 + gq * 32 + l31;

  const float* Qr = Qg + ((size_t)b * SEQ + qcol) * DIM;
  const char* Kt = Kws + (size_t)(b * NTILES + h * NT2) * KTB;
  const char* Vt = Vws + (size_t)(b * NTILES + h * NT2) * VTB;
  const unsigned* Lb = Lws + (size_t)b * SEQ + h * (NT2 * KVB);

  // Q fragments (B-operand): col = qcol, d-slot j of chunk c -> d = 16c + 8hi + j
  frag_u qf[8];
  #pragma unroll
  for (int c = 0; c < 8; ++c) {
    const float4 a = *(const float4*)(Qr + c * 16 + hi * 8);
    const float4 d = *(const float4*)(Qr + c * 16 + hi * 8 + 4);
    bf16x8 q8;
    q8[0]=f2bf(a.x); q8[1]=f2bf(a.y); q8[2]=f2bf(a.z); q8[3]=f2bf(a.w);
    q8[4]=f2bf(d.x); q8[5]=f2bf(d.y); q8[6]=f2bf(d.z); q8[7]=f2bf(d.w);
    qf[c].h = q8;
  }
  frag_u qpad;                       // pad B-frag: 1.0,1.0 in slots (hi=0, j=0,1)
  qpad.u[0] = (hi == 0) ? 0x3F803F80u : 0u;
  qpad.u[1] = qpad.u[2] = qpad.u[3] = 0u;

  f32x16 acc[4];
  #pragma unroll
  for (int nt = 0; nt < 4; ++nt)
    #pragma unroll
    for (int i = 0; i < 16; ++i) acc[nt][i] = 0.f;
  float lsum = 0.f;

  frag_u PAp[2];                     // packed P of previous tile (PV pending)
  frag_u vfr[8];                     // V fragments of previous tile (registers)

  auto ISSUE = [&](int t, int buf) {
    const char* ks = Kt + (size_t)t * KTB;
    const char* vs = Vt + (size_t)t * VTB;
    char* kl = smem + (h * 2 + buf) * 8192;
    char* vl = smem + 32768 + (h * 2 + buf) * 8192;
    #pragma unroll
    for (int j = 0; j < 2; ++j) {
      dma16(ks + j * 4096 + t128 * 16, kl + j * 4096 + t128 * 16);
      dma16(ks + j * 4096 + 2048 + t128 * 16, kl + j * 4096 + 2048 + t128 * 16);
      dma16(vs + j * 4096 + t128 * 16, vl + j * 4096 + t128 * 16);
      dma16(vs + j * 4096 + 2048 + t128 * 16, vl + j * 4096 + 2048 + t128 * 16);
    }
  };

  auto EXPPACK = [&](f32x16& S) {
    float p[16];
    #pragma unroll
    for (int i = 0; i < 16; ++i) {
      p[i] = __builtin_amdgcn_exp2f(S[i]);
      lsum += p[i];
    }
    #pragma unroll
    for (int ks = 0; ks < 2; ++ks) {
      unsigned a0 = cvtpk(p[8*ks+0], p[8*ks+1]);
      unsigned a1 = cvtpk(p[8*ks+2], p[8*ks+3]);
      unsigned b0 = cvtpk(p[8*ks+4], p[8*ks+5]);
      unsigned b1 = cvtpk(p[8*ks+6], p[8*ks+7]);
      pl32swap(a0, b0);
      pl32swap(a1, b1);
      PAp[ks].u[0] = a0; PAp[ks].u[1] = a1; PAp[ks].u[2] = b0; PAp[ks].u[3] = b1;
    }
  };

  auto LOADV = [&](const char* Vc) {
    #pragma unroll
    for (int g = 0; g < 8; ++g) {
      int nt = g >> 1, ks = g & 1;
      vfr[g].h = *(const bf16x8*)(Vc + (nt * 32 + l31) * 64 +
                  (((2 * ks + hi) ^ ((l31 >> 1) & 3)) << 4));
    }
  };

  ISSUE(0, 0);
  unsigned ltc = Lb[l31];
  __syncthreads();

  // ---- iteration 0 (peeled): QK(0) only; set up pipeline state ----
  {
    const char* Kc = smem;           // h*2+0 buffer
    const char* Vc = smem + 32768;
    const char* Kch = Kc + (h * 2) * 8192;
    const char* Vch = Vc + (h * 2) * 8192;
    ISSUE(1, 1);
    unsigned ltn = Lb[KVB + l31];

    f32x16 S;
    #pragma unroll
    for (int i = 0; i < 16; ++i) S[i] = 0.f;
    __builtin_amdgcn_s_setprio(1);
    #pragma unroll
    for (int c = 0; c < 8; ++c) {
      frag_u kfc;
      kfc.h = *(const bf16x8*)(Kch + l31 * 256 + (((2 * c + hi) ^ (l31 & 7)) << 4));
      S = __builtin_amdgcn_mfma_f32_32x32x16_bf16(kfc.h, qf[c].h, S, 0, 0, 0);
    }
    frag_u pa;
    pa.u[0] = (hi == 0) ? ltc : 0u;
    pa.u[1] = pa.u[2] = pa.u[3] = 0u;
    S = __builtin_amdgcn_mfma_f32_32x32x16_bf16(pa.h, qpad.h, S, 0, 0, 0);
    __builtin_amdgcn_s_setprio(0);

    EXPPACK(S);
    LOADV(Vch);
    ltc = ltn;
    __syncthreads();
  }

  // ---- main loop: QK(t) [LDS + dependent chain] interleaved with PV(t-1) [registers] ----
  for (int t = 1; t < NT2; ++t) {
    const int cur = t & 1;
    unsigned ltn = 0;
    if (t + 1 < NT2) {
      ISSUE(t + 1, cur ^ 1);        // overwrites tile t-1's buffers (K dead; V snapshotted)
      ltn = Lb[(t + 1) * KVB + l31];
    }
    const char* Kc = smem + (h * 2 + cur) * 8192;
    const char* Vc = smem + 32768 + (h * 2 + cur) * 8192;

    f32x16 S;
    #pragma unroll
    for (int i = 0; i < 16; ++i) S[i] = 0.f;
    __builtin_amdgcn_s_setprio(1);
    #pragma unroll
    for (int c = 0; c < 8; ++c) {
      frag_u kfc;
      kfc.h = *(const bf16x8*)(Kc + l31 * 256 + (((2 * c + hi) ^ (l31 & 7)) << 4));
      S = __builtin_amdgcn_mfma_f32_32x32x16_bf16(kfc.h, qf[c].h, S, 0, 0, 0);
      // independent stream: PV of previous tile, register-only operands
      acc[c >> 1] = __builtin_amdgcn_mfma_f32_32x32x16_bf16(vfr[c].h, PAp[c & 1].h, acc[c >> 1], 0, 0, 0);
    }
    frag_u pa;
    pa.u[0] = (hi == 0) ? ltc : 0u;
    pa.u[1] = pa.u[2] = pa.u[3] = 0u;
    S = __builtin_amdgcn_mfma_f32_32x32x16_bf16(pa.h, qpad.h, S, 0, 0, 0);
    __builtin_amdgcn_s_setprio(0);

    EXPPACK(S);                      // overwrites PAp with tile t's P
    LOADV(Vc);                       // snapshot V(t) before its buffer is overwritten
    ltc = ltn;
    __syncthreads();
  }

  // ---- drain: PV of last tile ----
  __builtin_amdgcn_s_setprio(1);
  #pragma unroll
  for (int c = 0; c < 8; ++c)
    acc[c >> 1] = __builtin_amdgcn_mfma_f32_32x32x16_bf16(vfr[c].h, PAp[c & 1].h, acc[c >> 1], 0, 0, 0);
  __builtin_amdgcn_s_setprio(0);

  // ---- epilogue: combine the two kv-halves in LDS (tiles dead after final barrier) ----
  const float Z = lsum + __shfl_xor(lsum, 32);   // both k-half-rows of this wave's tile
  float* AccX = (float*)smem;                    // [2 gq][32 q][128 d] f32 = 32 KB
  float* Zx   = (float*)(smem + 32768);          // [2 gq][32 q]
  const int q2 = gq * 32 + l31;

  if (h == 1) {
    if (hi == 0) Zx[q2] = Z;
    #pragma unroll
    for (int nt = 0; nt < 4; ++nt)
      #pragma unroll
      for (int j = 0; j < 4; ++j) {
        int d = nt * 32 + j * 8 + hi * 4;
        int byte_off = (q2 * 512 + d * 4) ^ ((l31 & 7) << 4);
        f32x4 qd;
        qd[0] = acc[nt][j*4+0]; qd[1] = acc[nt][j*4+1];
        qd[2] = acc[nt][j*4+2]; qd[3] = acc[nt][j*4+3];
        *(f32x4*)((char*)AccX + byte_off) = qd;
      }
  }
  __syncthreads();
  if (h == 0) {
    const float inv = 1.0f / (Z + Zx[q2]);
    float* orow = Og + ((size_t)b * SEQ + qcol) * DIM;
    #pragma unroll
    for (int nt = 0; nt < 4; ++nt)
      #pragma unroll
      for (int j = 0; j < 4; ++j) {
        int d = nt * 32 + j * 8 + hi * 4;
        int byte_off = (q2 * 512 + d * 4) ^ ((l31 & 7) << 4);
        f32x4 o = *(const f32x4*)((const char*)AccX + byte_off);
        float4 r;
        r.x = (acc[nt][j*4+0] + o[0]) * inv;
        r.y = (acc[nt][j*4+1] + o[1]) * inv;
        r.z = (acc[nt][j*4+2] + o[2]) * inv;
        r.w = (acc[nt][j*4+3] + o[3]) * inv;
        *(float4*)(orow + d) = r;
      }
  }
}

// ===== fallback (validated R3 monolithic) for small ws =====
__global__ __launch_bounds__(256, 2)
void trust_attn_fallback(const float* __restrict__ Qg, const float* __restrict__ Kg,
                         const float* __restrict__ Vg, const float* __restrict__ Tg,
                         float* __restrict__ Og) {
  __shared__ short Klds[2][64 * DIM];
  __shared__ short Vlds[2][DIM * 64];
  __shared__ short Plds[4][16 * 64];
  __shared__ float Tlds[2][64];

  const int b = blockIdx.y;
  const int qbase = blockIdx.x * 64;
  const int tid = (int)threadIdx.x;
  const int w = tid >> 6;
  const int l = tid & 63;
  const int lr = l & 15;
  const int lg = l >> 4;

  const float* Qb = Qg + (size_t)b * SEQ * DIM;
  const float* Kb = Kg + (size_t)b * SEQ * DIM;
  const float* Vb = Vg + (size_t)b * SEQ * DIM;
  const float* Tb = Tg + (size_t)b * SEQ;
  float*       Ob = Og + (size_t)b * SEQ * DIM;

  float4 kreg[8];
  float  vreg[32];
  float  treg;

  auto ISSUE = [&](int kv0) {
    #pragma unroll
    for (int i = 0; i < 8; ++i) {
      int flat4 = i * 256 + tid;
      int r = flat4 >> 5;
      int c4 = (flat4 & 31) << 2;
      kreg[i] = *(const float4*)(Kb + (size_t)(kv0 + r) * DIM + c4);
    }
    #pragma unroll
    for (int i = 0; i < 4; ++i) {
      int task = i * 256 + tid;
      int d = task & 127;
      int chunk = task >> 7;
      const float* src = Vb + (size_t)(kv0 + chunk * 8) * DIM + d;
      #pragma unroll
      for (int j = 0; j < 8; ++j) vreg[i * 8 + j] = src[(size_t)j * DIM];
    }
    treg = (tid < 64) ? Tb[kv0 + tid] : 0.f;
  };

  auto STORE = [&](int buf) {
    #pragma unroll
    for (int i = 0; i < 8; ++i) {
      int flat4 = i * 256 + tid;
      int r = flat4 >> 5;
      int c4 = (flat4 & 31) << 2;
      short4v pk;
      pk[0] = f2bf(kreg[i].x); pk[1] = f2bf(kreg[i].y);
      pk[2] = f2bf(kreg[i].z); pk[3] = f2bf(kreg[i].w);
      int byte_off = (r * 256 + (c4 << 1)) ^ ((r & 7) << 4);
      *(short4v*)((char*)&Klds[buf][0] + byte_off) = pk;
    }
    #pragma unroll
    for (int i = 0; i < 4; ++i) {
      int task = i * 256 + tid;
      int d = task & 127;
      int chunk = task >> 7;
      bf16x8 pk;
      #pragma unroll
      for (int j = 0; j < 8; ++j) pk[j] = f2bf(vreg[i * 8 + j]);
      int byte_off = (d * 128 + chunk * 16) ^ ((d & 7) << 4);
      *(bf16x8*)((char*)&Vlds[buf][0] + byte_off) = pk;
    }
    if (tid < 64) Tlds[buf][tid] = treg;
  };

  bf16x8 qf[4];
  {
    const float* qrow = Qb + (size_t)(qbase + w * 16 + lr) * DIM;
    #pragma unroll
    for (int kk = 0; kk < 4; ++kk) {
      const float4 a = *(const float4*)(qrow + kk * 32 + lg * 8);
      const float4 c = *(const float4*)(qrow + kk * 32 + lg * 8 + 4);
      bf16x8 f;
      f[0] = f2bf(a.x); f[1] = f2bf(a.y); f[2] = f2bf(a.z); f[3] = f2bf(a.w);
      f[4] = f2bf(c.x); f[5] = f2bf(c.y); f[6] = f2bf(c.z); f[7] = f2bf(c.w);
      qf[kk] = f;
    }
  }

  f32x4 acc[8];
  #pragma unroll
  for (int nt = 0; nt < 8; ++nt) acc[nt] = f32x4{0.f, 0.f, 0.f, 0.f};
  float lsum[4] = {0.f, 0.f, 0.f, 0.f};

  ISSUE(0);
  STORE(0);
  __syncthreads();

  for (int t = 0; t < SEQ / 64; ++t) {
    const int cur = t & 1;
    if (t + 1 < SEQ / 64) ISSUE((t + 1) * 64);

    const short* Kc = &Klds[cur][0];
    const short* Vc = &Vlds[cur][0];

    f32x4 s[4];
    #pragma unroll
    for (int kt = 0; kt < 4; ++kt) {
      f32x4 a0 = f32x4{0.f, 0.f, 0.f, 0.f};
      #pragma unroll
      for (int kk = 0; kk < 4; ++kk) {
        int row = kt * 16 + lr;
        int byte_off = (row * 256 + ((kk * 32 + lg * 8) << 1)) ^ ((row & 7) << 4);
        bf16x8 kf = *(const bf16x8*)((const char*)Kc + byte_off);
        a0 = __builtin_amdgcn_mfma_f32_16x16x32_bf16(qf[kk], kf, a0, 0, 0, 0);
      }
      s[kt] = a0;
    }

    short* Pw = Plds[w];
    #pragma unroll
    for (int kt = 0; kt < 4; ++kt) {
      float tt = Tlds[cur][kt * 16 + lr];
      float tc = tt * 0.12751743f;
      #pragma unroll
      for (int r = 0; r < 4; ++r) {
        float p = tt * exp2f(s[kt][r] * tc);
        lsum[r] += p;
        int q = lg * 4 + r;
        int byte_off = ((q * 128) + ((kt * 16 + lr) << 1)) ^ ((q & 7) << 4);
        *(short*)((char*)Pw + byte_off) = f2bf(p);
      }
    }
    asm volatile("s_waitcnt lgkmcnt(0)" ::: "memory");

    #pragma unroll
    for (int ks = 0; ks < 2; ++ks) {
      int byteA = (lr * 128 + ((ks * 32 + lg * 8) << 1)) ^ ((lr & 7) << 4);
      bf16x8 pf = *(const bf16x8*)((char*)Pw + byteA);
      #pragma unroll
      for (int nt = 0; nt < 8; ++nt) {
        int row = nt * 16 + lr;
        int byteB = (row * 128 + ((ks * 32 + lg * 8) << 1)) ^ ((row & 7) << 4);
        bf16x8 vf = *(const bf16x8*)((const char*)Vc + byteB);
        acc[nt] = __builtin_amdgcn_mfma_f32_16x16x32_bf16(pf, vf, acc[nt], 0, 0, 0);
      }
    }

    if (t + 1 < SEQ / 64) {
      STORE(cur ^ 1);
      __syncthreads();
    }
  }

  #pragma unroll
  for (int r = 0; r < 4; ++r) {
    float v = lsum[r];
    v += __shfl_xor(v, 1);
    v += __shfl_xor(v, 2);
    v += __shfl_xor(v, 4);
    v += __shfl_xor(v, 8);
    float inv = 1.0f / v;
    float* dst = Ob + (size_t)(qbase + w * 16 + lg * 4 + r) * DIM + lr;
    #pragma unroll
    for (int nt = 0; nt < 8; ++nt)
      dst[nt * 16] = acc[nt][r] * inv;
  }
}

extern "C" void kernel_launch(void* const* d_in, const int* in_sizes, int n_in,
                              void* d_out, int out_size, void* d_ws, size_t ws_size,
                              hipStream_t stream) {
  (void)n_in; (void)out_size;
  const float* Q = (const float*)d_in[0];
  const float* K = (const float*)d_in[1];
  const float* V = (const float*)d_in[2];
  const float* T = (const float*)d_in[3];
  float* O = (float*)d_out;
  const int B = in_sizes[0] / (SEQ * DIM);

  const size_t kv_bytes = (size_t)B * NTILES * KTB;  // per tensor (KTB==VTB)
  const size_t need = kv_bytes * 2 + (size_t)B * SEQ * sizeof(unsigned);
  if (ws_size >= need) {
    char* Kws = (char*)d_ws;
    char* Vws = Kws + kv_bytes;
    unsigned* Lws = (unsigned*)(Vws + kv_bytes);
    dim3 gridp(NTILES, B);
    prepack_kernel<<<gridp, 256, 0, stream>>>(K, V, T, Kws, Vws, Lws);
    const int nblk = B * (SEQ / 64);
    const int swz = (B == 16) ? 1 : 0;
    trust_attn_main<<<nblk, 256, 0, stream>>>(Q, Kws, Vws, Lws, O, swz);
  } else {
    dim3 grid(SEQ / 64, B);
    trust_attn_fallback<<<grid, 256, 0, stream>>>(Q, K, V, T, O);
  }
}